// Round 22
// baseline (5495.769 us; speedup 1.0000x reference)
//
#include <hip/hip_runtime.h>

// SNN-MNIST forward + STDP, MI355X persistent cooperative kernel.
// Round 26: phase-1 thread specialization (overlap gather with trace).
// r25 ledger: ~14 of 26.7 us/step sits in phase 1, whose trace and gather
// are SEQUENTIAL today despite no data dependency (gather needs only
// lst[t&1], written last step, and Wt, valid since the entry barrier; the
// only cross-thread value before the state update is s_any, ordered by the
// existing __syncthreads). New split:
//   tids 0-399: 64-load Wt gather + sum, issued IMMEDIATELY (no wv[64]
//               across any barrier -> no r23 VGPR blowup; disjoint threads)
//   tids 400-511: trace recurrence (7 elems each, i = (tid-400)+k*112,
//               single-writer; identical per-element arithmetic)
//   tids 448-511 additionally: anyspk (packed) + compaction of img[t+1]
// Per-output numerics bit-identical (same lst order, same recurrence).
// Everything else identical to r25 (register-resident syn/mem/post + W
// tile, 4-chunk phase 2, spread barf, packed anyspk, race-fix barrier).

#define T_STEPS 200
#define BATCH   256
#define INQ     784
#define NOUT    400
#define NP      512
#define GRID    256
#define NTHR    512
#define NBN     7              // n-blocks of 64 cols
#define ABLK    175            // 25 i-blocks x 7 n-blocks

// ws layout (float offsets)
#define OFF_WT    0            // Wt [785][512] (row 784 = zero pad for gather)
#define OFF_SPPO  606720       // interleaved (spk,post): [256][1024]  (sc1)
#define OFF_TRM   868864       // merged (tr,img): [256][1568]        (sc1)
#define OFF_ANY   1270528      // u32 anyspk[2][256] packed (sc1, ping-pong)
#define OFF_BARF  1274624      // u32 barf[256*8]: flags spread 32B apart
#define WS_FLOATS 1332224

// ---- agent-coherent (sc1) access helpers ----
__device__ __forceinline__ float ld_coh(const float* p) {
  return __hip_atomic_load(p, __ATOMIC_RELAXED, __HIP_MEMORY_SCOPE_AGENT);
}
__device__ __forceinline__ float2 ld_coh2(const float* p) {
  union { unsigned long long u; float2 f; } c;
  c.u = __hip_atomic_load((const unsigned long long*)p, __ATOMIC_RELAXED,
                          __HIP_MEMORY_SCOPE_AGENT);
  return c.f;
}
__device__ __forceinline__ void st_coh(float* p, float v) {
  __hip_atomic_store(p, v, __ATOMIC_RELAXED, __HIP_MEMORY_SCOPE_AGENT);
}
__device__ __forceinline__ void st_coh2(float* p, float2 v) {
  union { unsigned long long u; float2 f; } c; c.f = v;
  __hip_atomic_store((unsigned long long*)p, c.u, __ATOMIC_RELAXED,
                     __HIP_MEMORY_SCOPE_AGENT);
}
__device__ __forceinline__ void st_cohu(unsigned* p, unsigned v) {
  __hip_atomic_store(p, v, __ATOMIC_RELAXED, __HIP_MEMORY_SCOPE_AGENT);
}
__device__ __forceinline__ unsigned ld_cohu(const unsigned* p) {
  return __hip_atomic_load(p, __ATOMIC_RELAXED, __HIP_MEMORY_SCOPE_AGENT);
}
__device__ __forceinline__ unsigned long long ld_cohu64(const unsigned long long* p) {
  return __hip_atomic_load(p, __ATOMIC_RELAXED, __HIP_MEMORY_SCOPE_AGENT);
}

__device__ __forceinline__ void gl_lds16c(const float* g, float* l) {      // sc1
  __builtin_amdgcn_global_load_lds(
      (const __attribute__((address_space(1))) void*)g,
      (__attribute__((address_space(3))) void*)l, 16, 0, 0x10);
}

// All-to-all flag barrier, k = 1-based ordinal. Flags one per 32B
// (2 per 64B line): parallel store landing. Poll: lane l checks flags
// 4l..4l+3 (4 independent 4B sc1 loads); __all covers 256 blocks.
__device__ __forceinline__ void gbar(unsigned* barf, unsigned k, int blk) {
  __syncthreads();
  if (threadIdx.x == 0)
    st_cohu(barf + blk * 8, k);
  if (threadIdx.x < 64) {
    const unsigned* p = barf + (threadIdx.x << 5);   // flag 4l at (4l)*8
    for (;;) {
      unsigned f0 = ld_cohu(p);
      unsigned f1 = ld_cohu(p + 8);
      unsigned f2 = ld_cohu(p + 16);
      unsigned f3 = ld_cohu(p + 24);
      unsigned mn = min(min(f0, f1), min(f2, f3));
      if (__all(mn >= k)) break;
      __builtin_amdgcn_s_sleep(1);
    }
  }
  __syncthreads();
}

__global__ void __launch_bounds__(NTHR, 2) snn_kernel(
    const float* __restrict__ img,   // [200][256][784]
    const float* __restrict__ Win,   // [400][784]
    float* __restrict__ out,         // mem_rec | spk_rec | W_final
    float* ws)
{
  float* Wt    = ws + OFF_WT;
  float* sppo  = ws + OFF_SPPO;
  float* trm   = ws + OFF_TRM;
  unsigned* anyspk = (unsigned*)(ws + OFF_ANY);
  unsigned* barf   = (unsigned*)(ws + OFF_BARF);

  float* mem_rec = out;
  float* spk_rec = out + (size_t)T_STEPS * BATCH * NOUT;
  float* Wout    = out + (size_t)2 * T_STEPS * BATCH * NOUT;

  const int tid = threadIdx.x;
  const int blk = blockIdx.x;
  unsigned bt = 0;                    // barrier ordinal

  __shared__ float stg_ti[16384];     // merged (tr,img) [256][64], persistent
  __shared__ float stg_sp[2][8192];   // sppo chunk dbuf [64][128]
  __shared__ float s_trrow[INQ];      // block-own pre-trace row
  __shared__ int s_list[2][832];      // double-buffered active lists
  __shared__ int s_cnt2[2];
  __shared__ int s_any, s_win;
  __shared__ int s_red[8];

  // phase-2 geometry: 25 i-blocks (32 rows) x 7 n-blocks (64 cols)
  const int bi = blk / NBN, bn = blk % NBN;
  const int ib0 = bi * 32, nb0 = bn * 64;
  const int scol = 2 * nb0 + (tid & 31) * 4;        // sppo col
  int colf = 2 * ib0 + (tid & 15) * 4;
  if (colf > 2 * INQ - 4) colf = 2 * INQ - 4;

  // per-thread phase-2 tile: 2 i-rows x 2 n-cols
  const int ib = ib0 + (tid >> 5) * 2;
  const int nb = nb0 + (tid & 31) * 2;
  const int tioff = (tid >> 5) * 4;
  const int soff  = (tid & 31) * 4;
  const bool p2act = (blk < ABLK) && (ib < INQ) && (nb < NOUT);

  // persistent per-thread state (single-writer promotions)
  float syn_r = 0.f, mem_r = 0.f, pt_r = 0.f;
  float2 wl0 = {0.f, 0.f}, wl1 = {0.f, 0.f};

  // ---- init: Wt[i][n] = Win[n][i]; merged row {tr=0, img_0} ----
  for (int e = blk * NTHR + tid; e < NOUT * INQ; e += GRID * NTHR) {
    int n = e / INQ, i = e % INQ;
    st_coh(Wt + (size_t)i * NP + n, Win[e]);
  }
  for (int i = tid; i < INQ; i += NTHR)
    st_coh2(trm + (size_t)blk * (2 * INQ) + 2 * i,
            make_float2(0.0f, img[(size_t)blk * INQ + i]));
  for (int i = tid; i < INQ; i += NTHR) s_trrow[i] = 0.0f;
  if (tid == 0) s_win = 0;
  // init compaction of img[0] into s_list[0] (wave 0)
  if (tid < 64) {
    const float* im0 = img + (size_t)blk * INQ;
    int base = 0;
    for (int c = 0; c < INQ; c += 64) {
      int i = c + tid;
      bool act = (i < INQ) && (im0[i] != 0.0f);
      unsigned long long m = __ballot(act);
      if (act)
        s_list[0][base + (int)__popcll(m & ((1ull << tid) - 1ull))] = i;
      base += (int)__popcll(m);
    }
    if (tid == 0) {
      int cr = (base + 63) & ~63;
      for (int j = base; j < cr; ++j) s_list[0][j] = 784;
      s_cnt2[0] = cr;
    }
  }
  ++bt; gbar(barf, bt, blk);

  // W tile into persistent registers (single writer after init) +
  // step-0 ti prefetch (8 passes x 32 rows; lane-contiguous LDS dest)
  if (p2act) {
    wl0 = ld_coh2(Wt + (size_t)(ib + 0) * NP + nb);
    wl1 = ld_coh2(Wt + (size_t)(ib + 1) * NP + nb);
  }
  if (blk < ABLK) {
    #pragma unroll
    for (int q = 0; q < 8; ++q) {
      int br = q * 32 + (tid >> 4);
      gl_lds16c(trm + (size_t)br * (2 * INQ) + colf,
                &stg_ti[br * 64 + (tid & 15) * 4]);
    }
  }

  for (int t = 0; t < T_STEPS; ++t) {
    const int tn = (t + 1 < T_STEPS) ? t + 1 : t;

    // ================= phase 1: block b = batch row =================
    {
      const int b = blk;
      const float* imrow = img + ((size_t)t * BATCH + b) * INQ;
      const float* imnext = img + ((size_t)tn * BATCH + b) * INQ;
      float* trmrow = trm + (size_t)b * (2 * INQ);
      const int cnt = s_cnt2[t & 1];    // written last step, long synced
      const int* lst = s_list[t & 1];
      float c0 = 0.f;

      if (tid < NOUT) {
        // tids 0-399: gather immediately (Wt valid since entry barrier);
        // overlaps trace+compaction on tids 400-511
        for (int j = 0; j < cnt; j += 64) {  // 64 coherent loads in flight
          float wv[64];
          #pragma unroll
          for (int u = 0; u < 64; ++u)
            wv[u] = ld_coh(Wt + (size_t)lst[j + u] * NP + tid);
          #pragma unroll
          for (int u = 0; u < 64; ++u) c0 += wv[u];
        }
      } else {
        // tids 400-511: trace recurrence, 7 elems each (single-writer map)
        const int l0 = tid - 400;
        #pragma unroll
        for (int k = 0; k < 7; ++k) {
          int i = l0 + k * 112;
          float trv = fmaf(0.9f, s_trrow[i], imrow[i]);
          s_trrow[i] = trv;
          st_coh2(trmrow + 2 * i, make_float2(trv, imnext[i]));
        }
        if (tid >= 448) {
          // wave 7: anyspk gather (packed) + compaction of img[t+1]
          const int l = tid - 448;
          unsigned long long ax = 0ull, ay = 0ull;
          if (t > 0) {
            const unsigned long long* ap =
                (const unsigned long long*)(anyspk + ((t - 1) & 1) * 256) +
                (l << 1);
            ax = ld_cohu64(ap);
            ay = ld_cohu64(ap + 1);
          }
          int* lstn = s_list[(t + 1) & 1];
          int base = 0;
          for (int c = 0; c < INQ; c += 64) {
            int i = c + l;
            bool act = (i < INQ) && (imnext[i] != 0.0f);
            unsigned long long m = __ballot(act);
            if (act) lstn[base + (int)__popcll(m & ((1ull << l) - 1ull))] = i;
            base += (int)__popcll(m);
          }
          int anyv = __any((ax | ay) != 0ull);
          if (l == 0) {
            int cr = (base + 63) & ~63;
            for (int j = base; j < cr; ++j) lstn[j] = 784;  // zero pad row
            s_cnt2[(t + 1) & 1] = cr;
            s_any = anyv;
          }
        }
      }
      __syncthreads();
      const int anyPrev = (t > 0) ? s_any : 0;
      const int wPrev = s_win;
      int localmin = 0x7fffffff;

      if (tid < NOUT) {
        const int n0 = tid;             // one neuron per thread
        float sv = syn_r;
        if (anyPrev && n0 != wPrev) sv -= 0.1f;
        float syn0 = fmaf(0.9f, sv, c0);
        float r0 = (mem_r > 1.0f) ? 1.0f : 0.0f;
        float m0 = fmaf(0.8f, mem_r, syn0) - r0;
        float s0 = (m0 > 1.0f) ? 1.0f : 0.0f;
        syn_r = syn0;
        mem_r = m0;
        float p0 = fmaf(0.9f, pt_r, s0);
        pt_r = p0;
        st_coh2(sppo + (size_t)b * 1024 + 2 * n0, make_float2(s0, p0));
        const size_t ridx = (size_t)t * BATCH * NOUT + (size_t)b * NOUT + n0;
        mem_rec[ridx] = m0;
        spk_rec[ridx] = s0;
        if (s0 != 0.f) localmin = n0;
      }
      // ballot winner reduction
      unsigned long long mm = __ballot(localmin != 0x7fffffff);
      int wmin = 0x7fffffff;
      if (mm) {
        int src = __ffsll(mm) - 1;
        wmin = __shfl(localmin, src);
      }
      if ((tid & 63) == 0) s_red[tid >> 6] = wmin;
      __syncthreads();
      if (tid == 0) {
        int w4 = min(min(min(s_red[0], s_red[1]), min(s_red[2], s_red[3])),
                     min(min(s_red[4], s_red[5]), min(s_red[6], s_red[7])));
        s_win = (w4 == 0x7fffffff) ? 0 : w4;
        st_cohu(anyspk + (t & 1) * 256 + blk,
                (w4 != 0x7fffffff) ? 1u : 0u);
      }
    }
    ++bt; gbar(barf, bt, blk);

    // ================= phase 2: STDP weight update =================
    // ti resident in LDS; 4 merged chunks of 64 b-rows, 2-deep sppo dbuf.
    // W tile register-resident. Ledger: entry S0(4),S1(4); c=0 vmcnt(4)
    // retires S0; c>=1 vmcnt(0); SPSTG(c+1) after barrier(c).
    if (blk < ABLK) {
      float a00 = 0, a01 = 0, a10 = 0, a11 = 0;

      #define SPSTG(c_, buf_) {                                                \
        for (int q = 0; q < 4; ++q) {                                          \
          int br = (c_) * 64 + q * 16 + (tid >> 5);                            \
          gl_lds16c(sppo + (size_t)br * 1024 + scol,                           \
                    &stg_sp[buf_][(q * 16 + (tid >> 5)) * 128 +                \
                                  (tid & 31) * 4]);                            \
        }                                                                      \
      }

      SPSTG(0, 0); SPSTG(1, 1);
      for (int c = 0; c < 4; ++c) {
        if (c == 0) __builtin_amdgcn_s_waitcnt(0x0F74);  // vmcnt(4)
        else        __builtin_amdgcn_s_waitcnt(0x0F70);  // vmcnt(0)
        __builtin_amdgcn_sched_barrier(0);
        __builtin_amdgcn_s_barrier();
        if (c >= 1 && c <= 2) SPSTG(c + 1, (c + 1) & 1);
        if (p2act) {
          const float* Lti = &stg_ti[(c * 64) * 64 + tioff];
          const float* Lsp = &stg_sp[c & 1][soff];
          #pragma unroll 8
          for (int bb = 0; bb < 64; ++bb) {       // b ascending: exact order
            float4 q4 = *(const float4*)(Lti + bb * 64);   // tr0,im0,tr1,im1
            float4 sp = *(const float4*)(Lsp + bb * 128);  // s0,p0,s1,p1
            a00 = fmaf(q4.x, sp.x, fmaf(q4.y, -sp.y, a00));
            a01 = fmaf(q4.x, sp.z, fmaf(q4.y, -sp.w, a01));
            a10 = fmaf(q4.z, sp.x, fmaf(q4.w, -sp.y, a10));
            a11 = fmaf(q4.z, sp.z, fmaf(q4.w, -sp.w, a11));
          }
        }
      }
      #undef SPSTG

      // RACE FIX: all waves finish chunk-3 LDS reads before the prefetch
      // overwrites stg_ti.
      __builtin_amdgcn_s_barrier();

      // next-step ti prefetch streams in the epilogue + barrier shadow
      if (t + 1 < T_STEPS) {
        #pragma unroll
        for (int q = 0; q < 8; ++q) {
          int br = q * 32 + (tid >> 4);
          gl_lds16c(trm + (size_t)br * (2 * INQ) + colf,
                    &stg_ti[br * 64 + (tid & 15) * 4]);
        }
      }
      if (p2act) {
        wl0.x = fminf(fmaxf(wl0.x + 1e-3f * a00, 0.f), 1.f);
        wl0.y = fminf(fmaxf(wl0.y + 1e-3f * a01, 0.f), 1.f);
        st_coh2(Wt + (size_t)(ib + 0) * NP + nb, wl0);
        wl1.x = fminf(fmaxf(wl1.x + 1e-3f * a10, 0.f), 1.f);
        wl1.y = fminf(fmaxf(wl1.y + 1e-3f * a11, 0.f), 1.f);
        st_coh2(Wt + (size_t)(ib + 1) * NP + nb, wl1);
      }
    }
    ++bt; gbar(barf, bt, blk);
  }

  // ---- final: W_out[n][i] = Wt[i][n] ----
  for (int e = blk * NTHR + tid; e < NOUT * INQ; e += GRID * NTHR) {
    int n = e / INQ, i = e % INQ;
    Wout[e] = ld_coh(Wt + (size_t)i * NP + n);
  }
}

extern "C" void kernel_launch(void* const* d_in, const int* in_sizes, int n_in,
                              void* d_out, int out_size, void* d_ws, size_t ws_size,
                              hipStream_t stream) {
  const float* img = (const float*)d_in[0];
  const float* W   = (const float*)d_in[1];
  float* out = (float*)d_out;
  float* ws  = (float*)d_ws;

  hipMemsetAsync(d_ws, 0, (size_t)WS_FLOATS * sizeof(float), stream);

  void* args[] = { (void*)&img, (void*)&W, (void*)&out, (void*)&ws };
  hipError_t rc = hipLaunchCooperativeKernel((const void*)snn_kernel,
                                             dim3(GRID), dim3(NTHR),
                                             args, 0, stream);
  if (rc != hipSuccess) {
    // Hand-rolled grid barrier; ~141 KB LDS -> 1 block/CU, grid == #CUs:
    // co-residency holds by construction under a plain launch.
    hipLaunchKernelGGL(snn_kernel, dim3(GRID), dim3(NTHR), 0, stream,
                       img, W, out, ws);
  }
}

// Round 23
// 5353.522 us; speedup vs baseline: 1.0266x; 1.0266x over previous
//
#include <hip/hip_runtime.h>

// SNN-MNIST forward + STDP, MI355X persistent cooperative kernel.
// Round 27: CONSOLIDATION — byte-identical resubmission of the session's
// best verified kernel (r22: 5336 us bench / 5280 us counters). r23-r26
// explored {anyspk spread, gather hoist, register promotions, thread
// specialization}: all measured null-to-negative; r26 (current) is a
// regression, so the session must land on r22.
// Win attribution vs the 7717 us baseline (-31%):
//  - barrier flag spreading, 1 flag/32B (r21 measured 3.75us/barrier
//    release from 16-stores/line serialization; r22 fix: -5.1 us/step)
//  - TLP 256->512 threads (r13: -3.7 us/step; 1024 regresses, knee at 512)
//  - 4-chunk merged phase-2 + compaction prefetch (r20: -1.3 us/step)
//  - merged (tr,img) layout, 2 x b128/bb inner (r18: -0.9 us/step)
//  - phase-2 retile 32i x 64n + 175 active blocks (r19)
//  - race-fix barrier before ti prefetch (absmax 4.0 -> 2.0)
// Remaining ~26 us/step: ~7 VALU-issue, ~7 phase-2 LDS-throughput
// (r16-measured), ~2.4 barrier release (r21-measured), ~9-10 gather
// lambda + write-through drain + inter-block skew. Further reduction
// requires fp-order-changing restructures (MFMA phase-2, i-block-major
// FC) -- rejected: chaotic spike-threshold dynamics put a 434-scale
// error cliff behind the current absmax-2.0 margin.

#define T_STEPS 200
#define BATCH   256
#define INQ     784
#define NOUT    400
#define NP      512
#define GRID    256
#define NTHR    512
#define NBN     7              // n-blocks of 64 cols
#define ABLK    175            // 25 i-blocks x 7 n-blocks

// ws layout (float offsets)
#define OFF_WT    0            // Wt [785][512] (row 784 = zero pad for gather)
#define OFF_SYN   401920       // syn [256][400]         (block-private)
#define OFF_MEM   504320       // mem [256][400]         (block-private)
#define OFF_SPPO  606720       // interleaved (spk,post): [256][1024]  (sc1)
#define OFF_TRM   868864       // merged (tr,img): [256][1568]        (sc1)
#define OFF_WIN   1270272      // int win[256]           (block-private)
#define OFF_ANY   1270528      // u32 anyspk[2][256]     (sc1, ping-pong)
#define OFF_BARF  1274624      // u32 barf[256*8]: flags spread 32B apart
#define WS_FLOATS 1332224

// ---- agent-coherent (sc1) access helpers ----
__device__ __forceinline__ float ld_coh(const float* p) {
  return __hip_atomic_load(p, __ATOMIC_RELAXED, __HIP_MEMORY_SCOPE_AGENT);
}
__device__ __forceinline__ float2 ld_coh2(const float* p) {
  union { unsigned long long u; float2 f; } c;
  c.u = __hip_atomic_load((const unsigned long long*)p, __ATOMIC_RELAXED,
                          __HIP_MEMORY_SCOPE_AGENT);
  return c.f;
}
__device__ __forceinline__ void st_coh(float* p, float v) {
  __hip_atomic_store(p, v, __ATOMIC_RELAXED, __HIP_MEMORY_SCOPE_AGENT);
}
__device__ __forceinline__ void st_coh2(float* p, float2 v) {
  union { unsigned long long u; float2 f; } c; c.f = v;
  __hip_atomic_store((unsigned long long*)p, c.u, __ATOMIC_RELAXED,
                     __HIP_MEMORY_SCOPE_AGENT);
}
__device__ __forceinline__ void st_cohu(unsigned* p, unsigned v) {
  __hip_atomic_store(p, v, __ATOMIC_RELAXED, __HIP_MEMORY_SCOPE_AGENT);
}
__device__ __forceinline__ unsigned ld_cohu(const unsigned* p) {
  return __hip_atomic_load(p, __ATOMIC_RELAXED, __HIP_MEMORY_SCOPE_AGENT);
}
__device__ __forceinline__ unsigned long long ld_cohu64(const unsigned long long* p) {
  return __hip_atomic_load(p, __ATOMIC_RELAXED, __HIP_MEMORY_SCOPE_AGENT);
}

__device__ __forceinline__ void gl_lds16c(const float* g, float* l) {      // sc1
  __builtin_amdgcn_global_load_lds(
      (const __attribute__((address_space(1))) void*)g,
      (__attribute__((address_space(3))) void*)l, 16, 0, 0x10);
}

// All-to-all flag barrier, k = 1-based ordinal. Flags one per 32B
// (2 per 64B line): parallel store landing, no per-line serialization.
// Poll: lane l checks flags 4l..4l+3 (4 independent 4B sc1 loads = one
// round trip); __all over 64 lanes covers all 256 blocks.
__device__ __forceinline__ void gbar(unsigned* barf, unsigned k, int blk) {
  __syncthreads();
  if (threadIdx.x == 0)
    st_cohu(barf + blk * 8, k);
  if (threadIdx.x < 64) {
    const unsigned* p = barf + (threadIdx.x << 5);   // flag 4l at (4l)*8
    for (;;) {
      unsigned f0 = ld_cohu(p);
      unsigned f1 = ld_cohu(p + 8);
      unsigned f2 = ld_cohu(p + 16);
      unsigned f3 = ld_cohu(p + 24);
      unsigned mn = min(min(f0, f1), min(f2, f3));
      if (__all(mn >= k)) break;
      __builtin_amdgcn_s_sleep(1);
    }
  }
  __syncthreads();
}

__global__ void __launch_bounds__(NTHR, 2) snn_kernel(
    const float* __restrict__ img,   // [200][256][784]
    const float* __restrict__ Win,   // [400][784]
    float* __restrict__ out,         // mem_rec | spk_rec | W_final
    float* ws)
{
  float* Wt    = ws + OFF_WT;
  float* syn   = ws + OFF_SYN;
  float* mem   = ws + OFF_MEM;
  float* sppo  = ws + OFF_SPPO;
  float* trm   = ws + OFF_TRM;
  int*   win   = (int*)(ws + OFF_WIN);
  unsigned* anyspk = (unsigned*)(ws + OFF_ANY);
  unsigned* barf   = (unsigned*)(ws + OFF_BARF);

  float* mem_rec = out;
  float* spk_rec = out + (size_t)T_STEPS * BATCH * NOUT;
  float* Wout    = out + (size_t)2 * T_STEPS * BATCH * NOUT;

  const int tid = threadIdx.x;
  const int blk = blockIdx.x;
  unsigned bt = 0;                    // barrier ordinal

  __shared__ float stg_ti[16384];     // merged (tr,img) [256][64], persistent
  __shared__ float stg_sp[2][8192];   // sppo chunk dbuf [64][128]
  __shared__ float s_trrow[INQ];      // block-own pre-trace row
  __shared__ int s_list[2][832];      // double-buffered active lists
  __shared__ int s_cnt2[2];
  __shared__ int s_any;
  __shared__ int s_red[8];

  // phase-2 geometry: 25 i-blocks (32 rows) x 7 n-blocks (64 cols)
  const int bi = blk / NBN, bn = blk % NBN;
  const int ib0 = bi * 32, nb0 = bn * 64;
  const int scol = 2 * nb0 + (tid & 31) * 4;        // sppo col
  int colf = 2 * ib0 + (tid & 15) * 4;
  if (colf > 2 * INQ - 4) colf = 2 * INQ - 4;

  // per-thread phase-2 tile: 2 i-rows x 2 n-cols
  const int ib = ib0 + (tid >> 5) * 2;
  const int nb = nb0 + (tid & 31) * 2;
  const int tioff = (tid >> 5) * 4;
  const int soff  = (tid & 31) * 4;

  // ---- init: Wt[i][n] = Win[n][i]; merged row {tr=0, img_0} ----
  for (int e = blk * NTHR + tid; e < NOUT * INQ; e += GRID * NTHR) {
    int n = e / INQ, i = e % INQ;
    st_coh(Wt + (size_t)i * NP + n, Win[e]);
  }
  for (int i = tid; i < INQ; i += NTHR)
    st_coh2(trm + (size_t)blk * (2 * INQ) + 2 * i,
            make_float2(0.0f, img[(size_t)blk * INQ + i]));
  for (int i = tid; i < INQ; i += NTHR) s_trrow[i] = 0.0f;
  // init compaction of img[0] into s_list[0] (wave 0)
  if (tid < 64) {
    const float* im0 = img + (size_t)blk * INQ;
    int base = 0;
    for (int c = 0; c < INQ; c += 64) {
      int i = c + tid;
      bool act = (i < INQ) && (im0[i] != 0.0f);
      unsigned long long m = __ballot(act);
      if (act)
        s_list[0][base + (int)__popcll(m & ((1ull << tid) - 1ull))] = i;
      base += (int)__popcll(m);
    }
    if (tid == 0) {
      int cr = (base + 63) & ~63;
      for (int j = base; j < cr; ++j) s_list[0][j] = 784;
      s_cnt2[0] = cr;
    }
  }
  ++bt; gbar(barf, bt, blk);

  // step-0 ti prefetch (8 passes x 32 rows; lane-contiguous LDS dest)
  if (blk < ABLK) {
    #pragma unroll
    for (int q = 0; q < 8; ++q) {
      int br = q * 32 + (tid >> 4);
      gl_lds16c(trm + (size_t)br * (2 * INQ) + colf,
                &stg_ti[br * 64 + (tid & 15) * 4]);
    }
  }

  for (int t = 0; t < T_STEPS; ++t) {
    const int tn = (t + 1 < T_STEPS) ? t + 1 : t;

    // ================= phase 1: block b = batch row =================
    {
      const int b = blk;
      const float* imrow = img + ((size_t)t * BATCH + b) * INQ;
      const float* imnext = img + ((size_t)tn * BATCH + b) * INQ;
      float* trmrow = trm + (size_t)b * (2 * INQ);
      if (tid < 448) {
        // tids 0-447: trace recurrence from block-own LDS row; write merged
        // {tr_{t+1}, img_{t+1}} pair for next step's phase 2
        for (int i = tid; i < INQ; i += 448) {
          float trv = fmaf(0.9f, s_trrow[i], imrow[i]);
          s_trrow[i] = trv;
          st_coh2(trmrow + 2 * i, make_float2(trv, imnext[i]));
        }
      } else {
        // wave 7: anyspk gather + compaction of img[t+1] into buf[(t+1)&1]
        const int l = tid - 448;
        unsigned long long ax = 0ull, ay = 0ull;
        if (t > 0) {
          const unsigned long long* ap =
              (const unsigned long long*)(anyspk + ((t - 1) & 1) * 256) +
              (l << 1);
          ax = ld_cohu64(ap);
          ay = ld_cohu64(ap + 1);
        }
        int* lstn = s_list[(t + 1) & 1];
        int base = 0;
        for (int c = 0; c < INQ; c += 64) {
          int i = c + l;
          bool act = (i < INQ) && (imnext[i] != 0.0f);
          unsigned long long m = __ballot(act);
          if (act) lstn[base + (int)__popcll(m & ((1ull << l) - 1ull))] = i;
          base += (int)__popcll(m);
        }
        int anyv = __any((ax | ay) != 0ull);
        if (l == 0) {
          int cr = (base + 63) & ~63;
          for (int j = base; j < cr; ++j) lstn[j] = 784;  // zero pad row
          s_cnt2[(t + 1) & 1] = cr;
          s_any = anyv;
        }
      }
      __syncthreads();
      const int cnt = s_cnt2[t & 1];    // multiple of 64 (precomputed)
      const int* lst = s_list[t & 1];
      const int anyPrev = (t > 0) ? s_any : 0;
      const int wPrev = win[b];
      int localmin = 0x7fffffff;

      if (tid < NOUT) {
        const int n0 = tid;             // one neuron per thread
        const size_t sidx = (size_t)b * NOUT + n0;
        float* sprow = sppo + (size_t)b * 1024 + 2 * n0;
        float2 sp2 = ld_coh2(sprow);    // (spk, post)
        float sv = syn[sidx];
        if (anyPrev && n0 != wPrev) sv -= 0.1f;
        float c0 = 0.f;
        for (int j = 0; j < cnt; j += 64) {  // 64 coherent loads in flight
          float wv[64];
          #pragma unroll
          for (int u = 0; u < 64; ++u)
            wv[u] = ld_coh(Wt + (size_t)lst[j + u] * NP + n0);
          #pragma unroll
          for (int u = 0; u < 64; ++u) c0 += wv[u];
        }
        float mv = mem[sidx];
        float syn0 = fmaf(0.9f, sv, c0);
        float r0 = (mv > 1.0f) ? 1.0f : 0.0f;
        float m0 = fmaf(0.8f, mv, syn0) - r0;
        float s0 = (m0 > 1.0f) ? 1.0f : 0.0f;
        syn[sidx] = syn0;
        mem[sidx] = m0;
        float p0 = fmaf(0.9f, sp2.y, s0);
        st_coh2(sprow, make_float2(s0, p0));
        const size_t ridx = (size_t)t * BATCH * NOUT + (size_t)b * NOUT + n0;
        mem_rec[ridx] = m0;
        spk_rec[ridx] = s0;
        if (s0 != 0.f) localmin = n0;
      }
      // ballot winner reduction
      unsigned long long mm = __ballot(localmin != 0x7fffffff);
      int wmin = 0x7fffffff;
      if (mm) {
        int src = __ffsll(mm) - 1;
        wmin = __shfl(localmin, src);
      }
      if ((tid & 63) == 0) s_red[tid >> 6] = wmin;
      __syncthreads();
      if (tid == 0) {
        int w4 = min(min(min(s_red[0], s_red[1]), min(s_red[2], s_red[3])),
                     min(min(s_red[4], s_red[5]), min(s_red[6], s_red[7])));
        win[b] = (w4 == 0x7fffffff) ? 0 : w4;
        st_cohu(anyspk + (t & 1) * 256 + blk,
                (w4 != 0x7fffffff) ? 1u : 0u);
      }
    }
    ++bt; gbar(barf, bt, blk);

    // ================= phase 2: STDP weight update =================
    // ti resident in LDS; 4 merged chunks of 64 b-rows, 2-deep sppo dbuf.
    if (blk < ABLK) {
      const bool active = (ib < INQ) && (nb < NOUT);

      float2 wl0, wl1;
      if (active) {
        wl0 = ld_coh2(Wt + (size_t)(ib + 0) * NP + nb);
        wl1 = ld_coh2(Wt + (size_t)(ib + 1) * NP + nb);
      }

      float a00 = 0, a01 = 0, a10 = 0, a11 = 0;

      #define SPSTG(c_, buf_) {                                                \
        for (int q = 0; q < 4; ++q) {                                          \
          int br = (c_) * 64 + q * 16 + (tid >> 5);                            \
          gl_lds16c(sppo + (size_t)br * 1024 + scol,                           \
                    &stg_sp[buf_][(q * 16 + (tid >> 5)) * 128 +                \
                                  (tid & 31) * 4]);                            \
        }                                                                      \
      }

      SPSTG(0, 0); SPSTG(1, 1);
      for (int c = 0; c < 4; ++c) {
        if (c == 0) __builtin_amdgcn_s_waitcnt(0x0F74);  // vmcnt(4)
        else        __builtin_amdgcn_s_waitcnt(0x0F70);  // vmcnt(0)
        __builtin_amdgcn_sched_barrier(0);
        __builtin_amdgcn_s_barrier();
        if (c >= 1 && c <= 2) SPSTG(c + 1, (c + 1) & 1);
        if (active) {
          const float* Lti = &stg_ti[(c * 64) * 64 + tioff];
          const float* Lsp = &stg_sp[c & 1][soff];
          #pragma unroll 8
          for (int bb = 0; bb < 64; ++bb) {       // b ascending: exact order
            float4 q4 = *(const float4*)(Lti + bb * 64);   // tr0,im0,tr1,im1
            float4 sp = *(const float4*)(Lsp + bb * 128);  // s0,p0,s1,p1
            a00 = fmaf(q4.x, sp.x, fmaf(q4.y, -sp.y, a00));
            a01 = fmaf(q4.x, sp.z, fmaf(q4.y, -sp.w, a01));
            a10 = fmaf(q4.z, sp.x, fmaf(q4.w, -sp.y, a10));
            a11 = fmaf(q4.z, sp.z, fmaf(q4.w, -sp.w, a11));
          }
        }
      }
      #undef SPSTG

      // RACE FIX: all waves finish chunk-3 LDS reads before the prefetch
      // overwrites stg_ti.
      __builtin_amdgcn_s_barrier();

      // next-step ti prefetch streams in the epilogue + barrier shadow
      if (t + 1 < T_STEPS) {
        #pragma unroll
        for (int q = 0; q < 8; ++q) {
          int br = q * 32 + (tid >> 4);
          gl_lds16c(trm + (size_t)br * (2 * INQ) + colf,
                    &stg_ti[br * 64 + (tid & 15) * 4]);
        }
      }
      if (active) {
        float2 wv2;
        wv2 = wl0;
        wv2.x = fminf(fmaxf(wv2.x + 1e-3f * a00, 0.f), 1.f);
        wv2.y = fminf(fmaxf(wv2.y + 1e-3f * a01, 0.f), 1.f);
        st_coh2(Wt + (size_t)(ib + 0) * NP + nb, wv2);
        wv2 = wl1;
        wv2.x = fminf(fmaxf(wv2.x + 1e-3f * a10, 0.f), 1.f);
        wv2.y = fminf(fmaxf(wv2.y + 1e-3f * a11, 0.f), 1.f);
        st_coh2(Wt + (size_t)(ib + 1) * NP + nb, wv2);
      }
    }
    ++bt; gbar(barf, bt, blk);
  }

  // ---- final: W_out[n][i] = Wt[i][n] ----
  for (int e = blk * NTHR + tid; e < NOUT * INQ; e += GRID * NTHR) {
    int n = e / INQ, i = e % INQ;
    Wout[e] = ld_coh(Wt + (size_t)i * NP + n);
  }
}

extern "C" void kernel_launch(void* const* d_in, const int* in_sizes, int n_in,
                              void* d_out, int out_size, void* d_ws, size_t ws_size,
                              hipStream_t stream) {
  const float* img = (const float*)d_in[0];
  const float* W   = (const float*)d_in[1];
  float* out = (float*)d_out;
  float* ws  = (float*)d_ws;

  hipMemsetAsync(d_ws, 0, (size_t)WS_FLOATS * sizeof(float), stream);

  void* args[] = { (void*)&img, (void*)&W, (void*)&out, (void*)&ws };
  hipError_t rc = hipLaunchCooperativeKernel((const void*)snn_kernel,
                                             dim3(GRID), dim3(NTHR),
                                             args, 0, stream);
  if (rc != hipSuccess) {
    // Hand-rolled grid barrier; ~141 KB LDS -> 1 block/CU, grid == #CUs:
    // co-residency holds by construction under a plain launch.
    hipLaunchKernelGGL(snn_kernel, dim3(GRID), dim3(NTHR), 0, stream,
                       img, W, out, ws);
  }
}